// Round 6
// baseline (187.980 us; speedup 1.0000x reference)
//
#include <hip/hip_runtime.h>
#include <hip/hip_bf16.h>

#define B_ 8
#define N_ 2048
#define D_ 32
#define CAP 4096
#define EM1_DIAG 1.7182818284590452f   // e^1 - 1
#define M_   8.0f
#define EM_  2980.9579870417283f       // e^8

typedef __attribute__((ext_vector_type(8))) short short8;
typedef __attribute__((ext_vector_type(4))) float f32x4;

// ---------------------------------------------------------------------------
// Setup: bf16 copies of x,y (row-major, D=32 contiguous), half-norms
// ||row||^2/2, zero pair counters. Vectorized: float4 in, short8 out.
// ---------------------------------------------------------------------------
__global__ void setup_kernel(const float* __restrict__ x, const float* __restrict__ y,
                             unsigned short* __restrict__ xb, unsigned short* __restrict__ yb,
                             float* __restrict__ NX, float* __restrict__ NY,
                             int* __restrict__ cnt)
{
    int t = blockIdx.x * 256 + threadIdx.x;          // 0..32767
    const float* src = (t < 16384) ? x : y;
    unsigned short* dstb = (t < 16384) ? xb : yb;
    float* dstn = (t < 16384) ? NX : NY;
    int row = (t < 16384) ? t : (t - 16384);
    const float4* p = reinterpret_cast<const float4*>(src + (size_t)row * D_);
    float ss = 0.f;
    float4 v[8];
    #pragma unroll
    for (int k = 0; k < 8; k++) {
        v[k] = p[k];
        ss += v[k].x * v[k].x + v[k].y * v[k].y + v[k].z * v[k].z + v[k].w * v[k].w;
    }
    short8* dst8 = reinterpret_cast<short8*>(dstb + (size_t)row * D_);
    #pragma unroll
    for (int k = 0; k < 4; k++) {
        const float fv[8] = { v[2*k].x, v[2*k].y, v[2*k].z, v[2*k].w,
                              v[2*k+1].x, v[2*k+1].y, v[2*k+1].z, v[2*k+1].w };
        short8 o;
        #pragma unroll
        for (int e = 0; e < 8; e++) {
            __hip_bfloat16 h = __float2bfloat16(fv[e]);
            o[e] = *reinterpret_cast<const short*>(&h);
        }
        dst8[k] = o;
    }
    dstn[row] = ss * 0.5f;                           // ||r||^2 / 2
    if (t < 24) cnt[t] = 0;
}

// ---------------------------------------------------------------------------
// Pair discovery: scan the 3 Gram matrices (0=xx, 1=yy, 2=yx) with the MFMA
// tile test; emit (i, j, e^{G}-1) for every element with dist < 10.
// Grid = 3 x 8 x 32 rowblocks x 4 colchunks = 3072 blocks (12/CU) so the
// load->MFMA->max chain is hidden by occupancy (R5: 768 blocks, 25% occ).
// ---------------------------------------------------------------------------
__global__ __launch_bounds__(256) void discover_kernel(
    const unsigned short* __restrict__ xb, const unsigned short* __restrict__ yb,
    const float* __restrict__ NX, const float* __restrict__ NY,
    int* __restrict__ cnt, uint2* __restrict__ lists)
{
    int m = blockIdx.x >> 10;                         // matrix 0..2
    int rem = blockIdx.x & 1023;
    int batch = rem >> 7;                             // 8 batches
    int rem2 = rem & 127;
    int rowblk = rem2 >> 2;                           // 32 blocks of 64 rows
    int cchunk = rem2 & 3;                            // 4 chunks of 512 cols
    const unsigned short* rd = (m == 0) ? xb : yb;
    const float*          rN = (m == 0) ? NX : NY;
    const unsigned short* cd = (m == 1) ? yb : xb;
    const float*          cN = (m == 1) ? NY : NX;

    const int tid = threadIdx.x, lane = tid & 63, wv = tid >> 6;
    const int r0 = rowblk * 64;
    const size_t rowbase = (size_t)batch * N_ + r0;

    short8 afrag[4];
    f32x4 cinit[4];
    #pragma unroll
    for (int g = 0; g < 4; g++) {
        afrag[g] = *reinterpret_cast<const short8*>(
            rd + (rowbase + g * 16 + (lane & 15)) * D_ + (lane >> 4) * 8);
        float4 nv = *reinterpret_cast<const float4*>(
            rN + rowbase + g * 16 + (lane >> 4) * 4);
        cinit[g][0] = -nv.x; cinit[g][1] = -nv.y; cinit[g][2] = -nv.z; cinit[g][3] = -nv.w;
    }
    const unsigned short* cdB = cd + (size_t)batch * N_ * D_;
    const float* cNB = cN + batch * N_;
    const int slot = m * 8 + batch;
    uint2* L = lists + (size_t)slot * CAP;
    const int c0 = cchunk * 512 + wv * 128;

    #pragma unroll
    for (int cc = 0; cc < 8; ++cc) {
        int col = c0 + cc * 16 + (lane & 15);
        short8 bfrag = *reinterpret_cast<const short8*>(
            cdB + (size_t)col * D_ + (lane >> 4) * 8);
        float ny = cNB[col];
        f32x4 d[4];
        #pragma unroll
        for (int g = 0; g < 4; g++)
            d[g] = __builtin_amdgcn_mfma_f32_16x16x32_bf16(afrag[g], bfrag, cinit[g], 0, 0, 0);
        float m0 = fmaxf(fmaxf(d[0][0], d[0][1]), fmaxf(d[0][2], d[0][3]));
        float m1 = fmaxf(fmaxf(d[1][0], d[1][1]), fmaxf(d[1][2], d[1][3]));
        float m2 = fmaxf(fmaxf(d[2][0], d[2][1]), fmaxf(d[2][2], d[2][3]));
        float m3 = fmaxf(fmaxf(d[3][0], d[3][1]), fmaxf(d[3][2], d[3][3]));
        float mx = fmaxf(fmaxf(m0, m1), fmaxf(m2, m3));
        if (__any(mx > ny - 10.0f)) {
            #pragma unroll
            for (int g = 0; g < 4; g++) {
                #pragma unroll
                for (int r = 0; r < 4; r++) {
                    float dist = ny - d[g][r];
                    if (dist < 10.0f) {
                        int i = r0 + g * 16 + (lane >> 4) * 4 + r;
                        if (m == 2 || i != col) {
                            float Gv = __expf(-fmaxf(dist, 0.f));
                            float em1 = __expf(Gv) - 1.0f;
                            int idx = atomicAdd(&cnt[slot], 1);
                            if (idx < CAP)
                                L[idx] = make_uint2(((unsigned)i << 16) | (unsigned)col,
                                                    __float_as_uint(em1));
                        }
                    }
                }
            }
        }
    }
}

// tree-sum of 16 LDS partials (depth 4, broadcast reads)
__device__ __forceinline__ float tree16(const float* r) {
    return (((r[0] + r[1]) + (r[2] + r[3])) + ((r[4] + r[5]) + (r[6] + r[7])))
         + (((r[8] + r[9]) + (r[10] + r[11])) + ((r[12] + r[13]) + (r[14] + r[15])));
}

// ---------------------------------------------------------------------------
// Whole Sinkhorn loop, one block per batch. Fixed LSE shift M_ (c=w+f bounded
// => e^{c-M} in [4e-8,1], fp32-safe; verified absmax=0 in R5).
// 2 barriers per stage: every f/ew value is only read at the owning thread's
// indices, so phase3 (f-update) flows into the next stage's phase1 without a
// barrier; B2 separates stage-N scatter atomics from stage-N+1 acc re-init.
// ---------------------------------------------------------------------------
__global__ __launch_bounds__(1024) void sinkhorn_kernel(
    const float* __restrict__ a_in, const float* __restrict__ b_in,
    const int* __restrict__ cnt, const uint2* __restrict__ lists,
    float* __restrict__ out)
{
    __shared__ float f[4][N_];        // 0=fxx, 1=fyx, 2=fxy, 3=fyy
    __shared__ float ew[2][N_];       // e^{a-M}, e^{b-M}
    __shared__ float ev[4][N_];
    __shared__ float acc[4][N_];
    __shared__ float red2[4][16];
    __shared__ float resacc;

    const int batch = blockIdx.x;
    const int t = threadIdx.x, lane = t & 63, wv = t >> 6;

    const int nxx = min(cnt[0 * 8 + batch], CAP);
    const int nyy = min(cnt[1 * 8 + batch], CAP);
    const int nyx = min(cnt[2 * 8 + batch], CAP);
    const uint2* Lxx = lists + (size_t)(0 * 8 + batch) * CAP;
    const uint2* Lyy = lists + (size_t)(1 * 8 + batch) * CAP;
    const uint2* Lyx = lists + (size_t)(2 * 8 + batch) * CAP;

    // register-cache the first 2048 entries of each list (n ~ 300 typical)
    uint2 rxx[2], ryy[2], ryx[2];
    #pragma unroll
    for (int q = 0; q < 2; q++) {
        int p = t + 1024 * q;
        rxx[q] = (p < nxx) ? Lxx[p] : make_uint2(0u, 0u);
        ryy[q] = (p < nyy) ? Lyy[p] : make_uint2(0u, 0u);
        ryx[q] = (p < nyx) ? Lyx[p] : make_uint2(0u, 0u);
    }

    #pragma unroll
    for (int q = 0; q < 2; q++) {
        int j = t + 1024 * q;
        ew[0][j] = __expf(a_in[batch * N_ + j] - M_);
        ew[1][j] = __expf(b_in[batch * N_ + j] - M_);
        f[0][j] = 0.f; f[1][j] = 0.f; f[2][j] = 0.f; f[3][j] = 0.f;
    }
    if (t == 0) resacc = 0.f;
    __syncthreads();

    // --- stage A: fxx (xx, a+fxx, diag), fyx (yx, a+fxy), fyy (yy, b+fyy, diag)
    auto stageA = [&]() {
        float ss0 = 0.f, ss1 = 0.f, ss2 = 0.f;
        #pragma unroll
        for (int q = 0; q < 2; q++) {
            int j = t + 1024 * q;
            float e0 = ew[0][j] * __expf(f[0][j]); ev[0][j] = e0; acc[0][j] = e0 * EM1_DIAG; ss0 += e0;
            float e1 = ew[0][j] * __expf(f[2][j]); ev[1][j] = e1; acc[1][j] = 0.f;           ss1 += e1;
            float e2 = ew[1][j] * __expf(f[3][j]); ev[2][j] = e2; acc[2][j] = e2 * EM1_DIAG; ss2 += e2;
        }
        #pragma unroll
        for (int off = 1; off < 64; off <<= 1) {
            ss0 += __shfl_xor(ss0, off, 64);
            ss1 += __shfl_xor(ss1, off, 64);
            ss2 += __shfl_xor(ss2, off, 64);
        }
        if (lane == 0) { red2[0][wv] = ss0; red2[1][wv] = ss1; red2[2][wv] = ss2; }
        __syncthreads();                                   // B1
        float S0 = tree16(red2[0]), S1 = tree16(red2[1]), S2 = tree16(red2[2]);
        #pragma unroll
        for (int q = 0; q < 2; q++) {
            int p = t + 1024 * q;
            if (p < nxx) { uint2 e = rxx[q]; atomicAdd(&acc[0][e.x >> 16], ev[0][e.x & 0xFFFFu] * __uint_as_float(e.y)); }
            if (p < nyx) { uint2 e = ryx[q]; atomicAdd(&acc[1][e.x >> 16], ev[1][e.x & 0xFFFFu] * __uint_as_float(e.y)); }
            if (p < nyy) { uint2 e = ryy[q]; atomicAdd(&acc[2][e.x >> 16], ev[2][e.x & 0xFFFFu] * __uint_as_float(e.y)); }
        }
        for (int p = 2048 + t; p < nxx; p += 1024) { uint2 e = Lxx[p]; atomicAdd(&acc[0][e.x >> 16], ev[0][e.x & 0xFFFFu] * __uint_as_float(e.y)); }
        for (int p = 2048 + t; p < nyx; p += 1024) { uint2 e = Lyx[p]; atomicAdd(&acc[1][e.x >> 16], ev[1][e.x & 0xFFFFu] * __uint_as_float(e.y)); }
        for (int p = 2048 + t; p < nyy; p += 1024) { uint2 e = Lyy[p]; atomicAdd(&acc[2][e.x >> 16], ev[2][e.x & 0xFFFFu] * __uint_as_float(e.y)); }
        __syncthreads();                                   // B2
        #pragma unroll
        for (int q = 0; q < 2; q++) {
            int i = t + 1024 * q;
            f[0][i] = 0.5f * f[0][i] - 0.5f * (M_ + __logf(S0 + acc[0][i]));
            f[1][i] = 0.5f * f[1][i] - 0.5f * (M_ + __logf(S1 + acc[1][i]));
            f[3][i] = 0.5f * f[3][i] - 0.5f * (M_ + __logf(S2 + acc[2][i]));
        }
    };

    // --- stage B: fxy (xy matrix = yx^T, cols y, c = b + fyx_new)
    auto stageB = [&]() {
        float ss0 = 0.f;
        #pragma unroll
        for (int q = 0; q < 2; q++) {
            int j = t + 1024 * q;
            float e0 = ew[1][j] * __expf(f[1][j]); ev[0][j] = e0; acc[0][j] = 0.f; ss0 += e0;
        }
        #pragma unroll
        for (int off = 1; off < 64; off <<= 1) ss0 += __shfl_xor(ss0, off, 64);
        if (lane == 0) red2[0][wv] = ss0;
        __syncthreads();                                   // B1
        float S0 = tree16(red2[0]);
        #pragma unroll
        for (int q = 0; q < 2; q++) {
            int p = t + 1024 * q;
            if (p < nyx) { uint2 e = ryx[q]; atomicAdd(&acc[0][e.x & 0xFFFFu], ev[0][e.x >> 16] * __uint_as_float(e.y)); }
        }
        for (int p = 2048 + t; p < nyx; p += 1024) { uint2 e = Lyx[p]; atomicAdd(&acc[0][e.x & 0xFFFFu], ev[0][e.x >> 16] * __uint_as_float(e.y)); }
        __syncthreads();                                   // B2
        #pragma unroll
        for (int q = 0; q < 2; q++) {
            int i = t + 1024 * q;
            f[2][i] = 0.5f * f[2][i] - 0.5f * (M_ + __logf(S0 + acc[0][i]));
        }
    };

    for (int it = 0; it < 10; ++it) { stageA(); stageB(); }

    // --- stage E: 4 extrapolation LSEs + fused res reduce -------------------
    {
        float ss0 = 0.f, ss1 = 0.f, ss2 = 0.f, ss3 = 0.f;
        #pragma unroll
        for (int q = 0; q < 2; q++) {
            int j = t + 1024 * q;
            float e0 = ew[0][j] * __expf(f[0][j]); ev[0][j] = e0; acc[0][j] = e0 * EM1_DIAG; ss0 += e0; // xx
            float e1 = ew[0][j] * __expf(f[2][j]); ev[1][j] = e1; acc[1][j] = 0.f;           ss1 += e1; // yx
            float e2 = ew[1][j] * __expf(f[1][j]); ev[2][j] = e2; acc[2][j] = 0.f;           ss2 += e2; // xy
            float e3 = ew[1][j] * __expf(f[3][j]); ev[3][j] = e3; acc[3][j] = e3 * EM1_DIAG; ss3 += e3; // yy
        }
        #pragma unroll
        for (int off = 1; off < 64; off <<= 1) {
            ss0 += __shfl_xor(ss0, off, 64);
            ss1 += __shfl_xor(ss1, off, 64);
            ss2 += __shfl_xor(ss2, off, 64);
            ss3 += __shfl_xor(ss3, off, 64);
        }
        if (lane == 0) { red2[0][wv] = ss0; red2[1][wv] = ss1; red2[2][wv] = ss2; red2[3][wv] = ss3; }
        __syncthreads();                                   // B1
        float S0 = tree16(red2[0]), S1 = tree16(red2[1]), S2 = tree16(red2[2]), S3 = tree16(red2[3]);
        #pragma unroll
        for (int q = 0; q < 2; q++) {
            int p = t + 1024 * q;
            if (p < nxx) { uint2 e = rxx[q]; atomicAdd(&acc[0][e.x >> 16],      ev[0][e.x & 0xFFFFu] * __uint_as_float(e.y)); }
            if (p < nyx) { uint2 e = ryx[q]; atomicAdd(&acc[1][e.x >> 16],      ev[1][e.x & 0xFFFFu] * __uint_as_float(e.y));
                                             atomicAdd(&acc[2][e.x & 0xFFFFu], ev[2][e.x >> 16]      * __uint_as_float(e.y)); }
            if (p < nyy) { uint2 e = ryy[q]; atomicAdd(&acc[3][e.x >> 16],      ev[3][e.x & 0xFFFFu] * __uint_as_float(e.y)); }
        }
        for (int p = 2048 + t; p < nxx; p += 1024) { uint2 e = Lxx[p]; atomicAdd(&acc[0][e.x >> 16], ev[0][e.x & 0xFFFFu] * __uint_as_float(e.y)); }
        for (int p = 2048 + t; p < nyx; p += 1024) { uint2 e = Lyx[p]; atomicAdd(&acc[1][e.x >> 16], ev[1][e.x & 0xFFFFu] * __uint_as_float(e.y));
                                                     atomicAdd(&acc[2][e.x & 0xFFFFu], ev[2][e.x >> 16] * __uint_as_float(e.y)); }
        for (int p = 2048 + t; p < nyy; p += 1024) { uint2 e = Lyy[p]; atomicAdd(&acc[3][e.x >> 16], ev[3][e.x & 0xFFFFu] * __uint_as_float(e.y)); }
        __syncthreads();                                   // B2
        float ctr = 0.f;
        #pragma unroll
        for (int q = 0; q < 2; q++) {
            int i = t + 1024 * q;
            float r0 = M_ + __logf(S0 + acc[0][i]);   // lse_xx
            float r1 = M_ + __logf(S1 + acc[1][i]);   // lse_yx
            float r2 = M_ + __logf(S2 + acc[2][i]);   // lse_xy
            float r3 = M_ + __logf(S3 + acc[3][i]);   // lse_yy
            ctr += (r0 - r2) * ew[0][i] * EM_ + (r3 - r1) * ew[1][i] * EM_;
        }
        #pragma unroll
        for (int off = 1; off < 64; off <<= 1) ctr += __shfl_xor(ctr, off, 64);
        if (lane == 0) atomicAdd(&resacc, ctr);
        __syncthreads();
        if (t == 0) out[batch] = resacc;   // EPSILON = 1
    }
}

// ---------------------------------------------------------------------------
extern "C" void kernel_launch(void* const* d_in, const int* in_sizes, int n_in,
                              void* d_out, int out_size, void* d_ws, size_t ws_size,
                              hipStream_t stream)
{
    const float* x = (const float*)d_in[0];
    const float* a = (const float*)d_in[1];
    const float* y = (const float*)d_in[2];
    const float* b = (const float*)d_in[3];
    float* out = (float*)d_out;

    char* ws = (char*)d_ws;
    size_t o = 0;
    unsigned short* xb = (unsigned short*)(ws + o); o += (size_t)B_ * N_ * D_ * 2;
    unsigned short* yb = (unsigned short*)(ws + o); o += (size_t)B_ * N_ * D_ * 2;
    float* NX = (float*)(ws + o); o += (size_t)B_ * N_ * 4;
    float* NY = (float*)(ws + o); o += (size_t)B_ * N_ * 4;
    int* cnt = (int*)(ws + o); o += 128;
    uint2* lists = (uint2*)(ws + o); o += (size_t)3 * 8 * CAP * 8;

    setup_kernel<<<128, 256, 0, stream>>>(x, y, xb, yb, NX, NY, cnt);
    discover_kernel<<<3 * 1024, 256, 0, stream>>>(xb, yb, NX, NY, cnt, lists);
    sinkhorn_kernel<<<B_, 1024, 0, stream>>>(a, b, cnt, lists, out);
}